// Round 1
// baseline (667.638 us; speedup 1.0000x reference)
//
#include <hip/hip_runtime.h>

typedef float f32x4 __attribute__((ext_vector_type(4)));
typedef short s16x8 __attribute__((ext_vector_type(8)));

#define N_OUT 66049
#define M_DIM 1024
#define K_DIM 1024

// round-to-nearest-even f32 -> bf16 (finite inputs)
__device__ __forceinline__ ushort f2bf(float f) {
    union { float f; unsigned u; } x; x.f = f;
    unsigned r = x.u + 0x7fffu + ((x.u >> 16) & 1u);
    return (ushort)(r >> 16);
}

// 16B global -> LDS direct (wave-uniform LDS base + lane*16)
__device__ __forceinline__ void lds_load16(const void* g, void* l) {
    auto gp = reinterpret_cast<const __attribute__((address_space(1))) char*>(
        reinterpret_cast<uintptr_t>(g));
    auto lp = reinterpret_cast<__attribute__((address_space(3))) char*>(
        reinterpret_cast<uintptr_t>(l));
    __builtin_amdgcn_global_load_lds(gp, lp, 16, 0, 0);
}

// ---------------- x = concat(noise, embed[orders]) : [1024][116] ----------------
__global__ void build_x(const float* __restrict__ noise, const int* __restrict__ orders,
                        const float* __restrict__ emb, float* __restrict__ x)
{
    int idx = blockIdx.x * 256 + threadIdx.x;
    if (idx >= 1024 * 116) return;
    int b = idx / 116, c = idx - b * 116;
    float v = (c < 100) ? noise[b * 100 + c] : emb[orders[b] * 16 + (c - 100)];
    x[idx] = v;
}

// ---------------- small fp32 GEMM: C = relu(A@W + b), 64x64 tile ----------------
template <bool OUT_BF16>
__global__ __launch_bounds__(256) void gemm_relu(
    const float* __restrict__ A, const float* __restrict__ W,
    const float* __restrict__ bias, void* __restrict__ Cout,
    int M, int N, int K)
{
    __shared__ __align__(16) float As[16][68];  // [k][m], padded
    __shared__ __align__(16) float Ws[16][68];  // [k][n], padded
    const int tid = threadIdx.x;
    const int m0 = blockIdx.x * 64, n0 = blockIdx.y * 64;
    const int tr = tid >> 4, tc = tid & 15;
    float acc[4][4] = {};
    for (int k0 = 0; k0 < K; k0 += 16) {
        #pragma unroll
        for (int e = 0; e < 4; ++e) {
            int idx = e * 256 + tid;
            int r = idx >> 4, c = idx & 15;
            As[c][r] = (k0 + c < K) ? A[(size_t)(m0 + r) * K + k0 + c] : 0.f;
            int rw = idx >> 6, cw = idx & 63;
            Ws[rw][cw] = (k0 + rw < K) ? W[(size_t)(k0 + rw) * N + n0 + cw] : 0.f;
        }
        __syncthreads();
        #pragma unroll
        for (int kk = 0; kk < 16; ++kk) {
            f32x4 a = *reinterpret_cast<const f32x4*>(&As[kk][tr * 4]);
            f32x4 b = *reinterpret_cast<const f32x4*>(&Ws[kk][tc * 4]);
            #pragma unroll
            for (int i = 0; i < 4; ++i)
                #pragma unroll
                for (int j = 0; j < 4; ++j)
                    acc[i][j] = fmaf(a[i], b[j], acc[i][j]);
        }
        __syncthreads();
    }
    f32x4 bo = *reinterpret_cast<const f32x4*>(&bias[n0 + tc * 4]);
    #pragma unroll
    for (int i = 0; i < 4; ++i) {
        int m = m0 + tr * 4 + i;
        if (OUT_BF16) {
            ushort4 u;
            u.x = f2bf(fmaxf(acc[i][0] + bo[0], 0.f));
            u.y = f2bf(fmaxf(acc[i][1] + bo[1], 0.f));
            u.z = f2bf(fmaxf(acc[i][2] + bo[2], 0.f));
            u.w = f2bf(fmaxf(acc[i][3] + bo[3], 0.f));
            *reinterpret_cast<ushort4*>(&((ushort*)Cout)[(size_t)m * N + n0 + tc * 4]) = u;
        } else {
            f32x4 v;
            #pragma unroll
            for (int j = 0; j < 4; ++j) v[j] = fmaxf(acc[i][j] + bo[j], 0.f);
            *reinterpret_cast<f32x4*>(&((float*)Cout)[(size_t)m * N + n0 + tc * 4]) = v;
        }
    }
}

// ---------------- big GEMM: out = sigmoid(h3(bf16) @ Wout(f32->bf16) + bout) ----------------
// 128x128 tile, BK=64, 4 waves (2x2), mfma_f32_16x16x32_bf16, double-buffered LDS.
__global__ __launch_bounds__(256, 2) void gemm_out(
    const ushort* __restrict__ h3, const float* __restrict__ Wout,
    const float* __restrict__ bout, float* __restrict__ out)
{
    // A: [row r][k-unit c] with unit = 8 bf16 = 16B, XOR-swizzled c ^= (r&7)
    __shared__ __align__(16) ushort Alds[2][128 * 64];
    // B: [kb(8)][n(128)][kj(8)] k-major subtiles -> ds_read_b128 fragments
    __shared__ __align__(16) ushort Blds[2][64 * 128];

    const int tid = threadIdx.x;
    const int lane = tid & 63;
    const int w = tid >> 6;
    const int wm = w >> 1, wn = w & 1;

    // XCD-grouped mapping: raw = 64a + 8b + c -> xcd c handles panel a*8+c, mblk b.
    const int raw = blockIdx.x;
    const int panel = (raw >> 6) * 8 + (raw & 7);
    const int mblk = (raw >> 3) & 7;
    if (panel >= 517) return;
    const int m0 = mblk * 128;
    const int n0 = panel * 128;

    // B staging: thread owns column (n0+nl), kb = kb0 + 2g
    const int nl = tid & 127;
    const int kb0 = tid >> 7;
    int nc = n0 + nl; if (nc > N_OUT - 1) nc = N_OUT - 1;  // clamp (garbage cols never stored)
    const float* Bsrc = Wout + nc;

    f32x4 acc[4][4] = {};
    float breg[32];

    const int arow = wm * 64 + (lane & 15);  // + fm*16
    const int ac0  = lane >> 4;
    const int bn   = wn * 64 + (lane & 15);  // + fn*16

    auto stageA = [&](int buf, int kt) {
        const int k0 = kt * 64;
        #pragma unroll
        for (int i = 0; i < 4; ++i) {
            const int u = (w * 4 + i) * 64 + lane;       // linear 16B unit in LDS
            const int r = u >> 3, cc = u & 7;
            // inverse-swizzled global source, linear LDS dest (rule #21)
            const ushort* src = h3 + (size_t)(m0 + r) * K_DIM + (k0 + ((cc ^ (r & 7)) << 3));
            lds_load16(src, (void*)&Alds[buf][(w * 4 + i) * 512]);
        }
    };
    auto loadB = [&](int kt) {
        const int k0 = kt * 64;
        #pragma unroll
        for (int g = 0; g < 4; ++g) {
            const int kb = kb0 + g * 2;
            #pragma unroll
            for (int i = 0; i < 8; ++i)
                breg[g * 8 + i] = Bsrc[(size_t)(k0 + kb * 8 + i) * N_OUT];
        }
    };
    auto writeB = [&](int buf) {
        #pragma unroll
        for (int g = 0; g < 4; ++g) {
            const int kb = kb0 + g * 2;
            s16x8 v;
            #pragma unroll
            for (int i = 0; i < 8; ++i) v[i] = (short)f2bf(breg[g * 8 + i]);
            *reinterpret_cast<s16x8*>(&Blds[buf][(kb * 128 + nl) * 8]) = v;
        }
    };
    auto compute = [&](int buf) {
        #pragma unroll
        for (int ks = 0; ks < 2; ++ks) {
            s16x8 af[4], bfr[4];
            #pragma unroll
            for (int fm = 0; fm < 4; ++fm) {
                const int r = arow + fm * 16;
                const int cc = (ks * 4 + ac0) ^ (r & 7);
                af[fm] = *reinterpret_cast<const s16x8*>(&Alds[buf][r * 64 + cc * 8]);
            }
            const int kb = ks * 4 + ac0;
            #pragma unroll
            for (int fn = 0; fn < 4; ++fn)
                bfr[fn] = *reinterpret_cast<const s16x8*>(&Blds[buf][(kb * 128 + bn + fn * 16) * 8]);
            #pragma unroll
            for (int fm = 0; fm < 4; ++fm)
                #pragma unroll
                for (int fn = 0; fn < 4; ++fn)
                    acc[fm][fn] = __builtin_amdgcn_mfma_f32_16x16x32_bf16(
                        af[fm], bfr[fn], acc[fm][fn], 0, 0, 0);
        }
    };

    // prologue
    stageA(0, 0);
    loadB(0);
    writeB(0);
    __syncthreads();

    for (int kt = 0; kt < 16; ++kt) {
        const int buf = kt & 1;
        if (kt + 1 < 16) {
            stageA(buf ^ 1, kt + 1);   // issue direct-to-LDS A loads for next tile
            loadB(kt + 1);             // issue B global loads for next tile
        }
        compute(buf);                  // ds_read + 32 MFMA on current tile
        if (kt + 1 < 16) writeB(buf ^ 1);  // cvt + ds_write next tile's B
        __syncthreads();
    }

    // epilogue: sigmoid(acc + b_out), C/D layout col=lane&15, row=(lane>>4)*4+j
    const int rbase = m0 + wm * 64 + (lane >> 4) * 4;
    #pragma unroll
    for (int fn = 0; fn < 4; ++fn) {
        const int col = n0 + wn * 64 + fn * 16 + (lane & 15);
        const bool ok = col < N_OUT;
        const float bo = bout[ok ? col : (N_OUT - 1)];
        #pragma unroll
        for (int fm = 0; fm < 4; ++fm) {
            #pragma unroll
            for (int j = 0; j < 4; ++j) {
                if (ok) {
                    const int row = rbase + fm * 16 + j;
                    const float z = acc[fm][fn][j] + bo;
                    out[(size_t)row * N_OUT + col] = 1.f / (1.f + __expf(-z));
                }
            }
        }
    }
}

extern "C" void kernel_launch(void* const* d_in, const int* in_sizes, int n_in,
                              void* d_out, int out_size, void* d_ws, size_t ws_size,
                              hipStream_t stream)
{
    const float* noise = (const float*)d_in[0];
    const int*   orders = (const int*)d_in[1];
    const float* emb   = (const float*)d_in[2];
    const float* W1 = (const float*)d_in[3];
    const float* b1 = (const float*)d_in[4];
    const float* W2 = (const float*)d_in[5];
    const float* b2 = (const float*)d_in[6];
    const float* W3 = (const float*)d_in[7];
    const float* b3 = (const float*)d_in[8];
    const float* Wout = (const float*)d_in[9];
    const float* bout = (const float*)d_in[10];

    char* ws = (char*)d_ws;
    float*  x  = (float*)(ws);               // 1024*116*4 = 475 KB
    float*  h1 = (float*)(ws + 0x80000);     // 1024*256*4 = 1 MB
    float*  h2 = (float*)(ws + 0x180000);    // 1024*512*4 = 2 MB
    ushort* h3 = (ushort*)(ws + 0x380000);   // 1024*1024*2 = 2 MB (bf16)

    build_x<<<464, 256, 0, stream>>>(noise, orders, emb, x);
    gemm_relu<false><<<dim3(16, 4),  256, 0, stream>>>(x,  W1, b1, (void*)h1, 1024, 256,  116);
    gemm_relu<false><<<dim3(16, 8),  256, 0, stream>>>(h1, W2, b2, (void*)h2, 1024, 512,  256);
    gemm_relu<true ><<<dim3(16, 16), 256, 0, stream>>>(h2, W3, b3, (void*)h3, 1024, 1024, 512);
    gemm_out<<<4160, 256, 0, stream>>>(h3, Wout, bout, (float*)d_out);
}

// Round 2
// 538.607 us; speedup vs baseline: 1.2396x; 1.2396x over previous
//
#include <hip/hip_runtime.h>

typedef float f32x4 __attribute__((ext_vector_type(4)));
typedef short s16x8 __attribute__((ext_vector_type(8)));

#define N_OUT 66049
#define M_DIM 1024
#define K_DIM 1024
#define NPANEL 517           // ceil(66049/128)

// round-to-nearest-even f32 -> bf16 (finite inputs)
__device__ __forceinline__ ushort f2bf(float f) {
    union { float f; unsigned u; } x; x.f = f;
    unsigned r = x.u + 0x7fffu + ((x.u >> 16) & 1u);
    return (ushort)(r >> 16);
}

// 16B global -> LDS direct (wave-uniform LDS base + lane*16; global addr per-lane)
__device__ __forceinline__ void lds_load16(const void* g, void* l) {
    auto gp = reinterpret_cast<const __attribute__((address_space(1))) char*>(
        reinterpret_cast<uintptr_t>(g));
    auto lp = reinterpret_cast<__attribute__((address_space(3))) char*>(
        reinterpret_cast<uintptr_t>(l));
    __builtin_amdgcn_global_load_lds(gp, lp, 16, 0, 0);
}

// ---------------- x = concat(noise, embed[orders]) : [1024][116] ----------------
__global__ void build_x(const float* __restrict__ noise, const int* __restrict__ orders,
                        const float* __restrict__ emb, float* __restrict__ x)
{
    int idx = blockIdx.x * 256 + threadIdx.x;
    if (idx >= 1024 * 116) return;
    int b = idx / 116, c = idx - b * 116;
    float v = (c < 100) ? noise[b * 100 + c] : emb[orders[b] * 16 + (c - 100)];
    x[idx] = v;
}

// ---------------- small fp32 GEMM: C = relu(A@W + b), 64x64 tile ----------------
template <bool OUT_BF16>
__global__ __launch_bounds__(256) void gemm_relu(
    const float* __restrict__ A, const float* __restrict__ W,
    const float* __restrict__ bias, void* __restrict__ Cout,
    int M, int N, int K)
{
    __shared__ __align__(16) float As[16][68];  // [k][m], padded
    __shared__ __align__(16) float Ws[16][68];  // [k][n], padded
    const int tid = threadIdx.x;
    const int m0 = blockIdx.x * 64, n0 = blockIdx.y * 64;
    const int tr = tid >> 4, tc = tid & 15;
    float acc[4][4] = {};
    for (int k0 = 0; k0 < K; k0 += 16) {
        #pragma unroll
        for (int e = 0; e < 4; ++e) {
            int idx = e * 256 + tid;
            int r = idx >> 4, c = idx & 15;
            As[c][r] = (k0 + c < K) ? A[(size_t)(m0 + r) * K + k0 + c] : 0.f;
            int rw = idx >> 6, cw = idx & 63;
            Ws[rw][cw] = (k0 + rw < K) ? W[(size_t)(k0 + rw) * N + n0 + cw] : 0.f;
        }
        __syncthreads();
        #pragma unroll
        for (int kk = 0; kk < 16; ++kk) {
            f32x4 a = *reinterpret_cast<const f32x4*>(&As[kk][tr * 4]);
            f32x4 b = *reinterpret_cast<const f32x4*>(&Ws[kk][tc * 4]);
            #pragma unroll
            for (int i = 0; i < 4; ++i)
                #pragma unroll
                for (int j = 0; j < 4; ++j)
                    acc[i][j] = fmaf(a[i], b[j], acc[i][j]);
        }
        __syncthreads();
    }
    f32x4 bo = *reinterpret_cast<const f32x4*>(&bias[n0 + tc * 4]);
    #pragma unroll
    for (int i = 0; i < 4; ++i) {
        int m = m0 + tr * 4 + i;
        if (OUT_BF16) {
            ushort4 u;
            u.x = f2bf(fmaxf(acc[i][0] + bo[0], 0.f));
            u.y = f2bf(fmaxf(acc[i][1] + bo[1], 0.f));
            u.z = f2bf(fmaxf(acc[i][2] + bo[2], 0.f));
            u.w = f2bf(fmaxf(acc[i][3] + bo[3], 0.f));
            *reinterpret_cast<ushort4*>(&((ushort*)Cout)[(size_t)m * N + n0 + tc * 4]) = u;
        } else {
            f32x4 v;
            #pragma unroll
            for (int j = 0; j < 4; ++j) v[j] = fmaxf(acc[i][j] + bo[j], 0.f);
            *reinterpret_cast<f32x4*>(&((float*)Cout)[(size_t)m * N + n0 + tc * 4]) = v;
        }
    }
}

// ---------------- convert W_out (f32 [K][N]) -> Bp (bf16, [panel][kb][nl][kj8]) ----------------
// Bp unit u = ((panel*128 + kb)*128 + nl); holds k = kb*8+kj, col = panel*128+nl.
// Each k-tile (panel, kt) is then a contiguous 16 KB chunk -> global_load_lds, linear LDS.
__global__ __launch_bounds__(256) void convert_wout(
    const float* __restrict__ Wout, ushort* __restrict__ Bp)
{
    const size_t u = (size_t)blockIdx.x * 256 + threadIdx.x;   // < 517*128*128
    const int nl = (int)(u & 127);
    const int kb = (int)((u >> 7) & 127);
    const int p  = (int)(u >> 14);
    int col = p * 128 + nl;
    if (col > N_OUT - 1) col = N_OUT - 1;   // last panel: clamp (cols never stored)
    const float* src = Wout + (size_t)(kb * 8) * N_OUT + col;
    s16x8 v;
    #pragma unroll
    for (int i = 0; i < 8; ++i) v[i] = (short)f2bf(src[(size_t)i * N_OUT]);
    *reinterpret_cast<s16x8*>(Bp + u * 8) = v;
}

// ---------------- big GEMM: out = sigmoid(h3(bf16) @ Bp(bf16) + bout) ----------------
// m97 structure: 128x128 tile, BK=64, 4 waves (2x2), single-buffer LDS, 2 barriers/K-step.
__global__ __launch_bounds__(256, 3) void gemm_out(
    const ushort* __restrict__ h3, const ushort* __restrict__ Bp,
    const float* __restrict__ bout, float* __restrict__ out)
{
    // A: [row r][16B-unit cc], cc XOR-swizzled by (r&7): LDS[r][cc] = global[r][cc^(r&7)]
    __shared__ __align__(16) ushort Alds[128 * 64];
    // B: [kbl(8)][nl(128)][kj(8)] — matches Bp global layout (linear copy)
    __shared__ __align__(16) ushort Blds[64 * 128];

    const int tid = threadIdx.x;
    const int lane = tid & 63;
    const int w = tid >> 6;
    const int wm = w >> 1, wn = w & 1;

    // XCD-grouped mapping: 8 m-blocks of a panel land on one XCD (B panel L2 reuse)
    const int raw = blockIdx.x;
    const int panel = (raw >> 6) * 8 + (raw & 7);
    const int mblk = (raw >> 3) & 7;
    if (panel >= NPANEL) return;
    const int m0 = mblk * 128;
    const int n0 = panel * 128;

    f32x4 acc[4][4] = {};

    const int arow = wm * 64 + (lane & 15);  // + fm*16
    const int ac0  = lane >> 4;
    const int bn   = wn * 64 + (lane & 15);  // + fn*16

    const ushort* BpPanel = Bp + (size_t)panel * (128 * 128 * 8);

    for (int kt = 0; kt < 16; ++kt) {
        const int k0 = kt * 64;
        // ---- stage A (16 KB) : 4 global_load_lds per thread, swizzled source ----
        #pragma unroll
        for (int i = 0; i < 4; ++i) {
            const int u = (w * 4 + i) * 64 + lane;       // linear 16B unit
            const int r = u >> 3, cc = u & 7;
            const ushort* src = h3 + (size_t)(m0 + r) * K_DIM + (k0 + ((cc ^ (r & 7)) << 3));
            lds_load16(src, (void*)&Alds[(w * 4 + i) * 512]);
        }
        // ---- stage B (16 KB) : contiguous chunk, linear copy ----
        const ushort* bsrc = BpPanel + (size_t)kt * 8192;
        #pragma unroll
        for (int i = 0; i < 4; ++i) {
            const int u = (w * 4 + i) * 64 + lane;
            lds_load16(bsrc + (size_t)u * 8, (void*)&Blds[(w * 4 + i) * 512]);
        }
        __syncthreads();   // compiler drains vmcnt(0) here

        // ---- compute: 16 ds_read_b128 + 32 MFMA per thread ----
        #pragma unroll
        for (int ks = 0; ks < 2; ++ks) {
            s16x8 af[4], bfr[4];
            #pragma unroll
            for (int fm = 0; fm < 4; ++fm) {
                const int r = arow + fm * 16;
                const int cc = (ks * 4 + ac0) ^ (r & 7);
                af[fm] = *reinterpret_cast<const s16x8*>(&Alds[r * 64 + cc * 8]);
            }
            const int kbl = ks * 4 + ac0;
            #pragma unroll
            for (int fn = 0; fn < 4; ++fn)
                bfr[fn] = *reinterpret_cast<const s16x8*>(&Blds[(kbl * 128 + bn + fn * 16) * 8]);
            #pragma unroll
            for (int fm = 0; fm < 4; ++fm)
                #pragma unroll
                for (int fn = 0; fn < 4; ++fn)
                    acc[fm][fn] = __builtin_amdgcn_mfma_f32_16x16x32_bf16(
                        af[fm], bfr[fn], acc[fm][fn], 0, 0, 0);
        }
        __syncthreads();
    }

    // epilogue: sigmoid(acc + b_out); C/D layout col=lane&15, row=(lane>>4)*4+j
    const int rbase = m0 + wm * 64 + (lane >> 4) * 4;
    #pragma unroll
    for (int fn = 0; fn < 4; ++fn) {
        const int col = n0 + wn * 64 + fn * 16 + (lane & 15);
        const bool ok = col < N_OUT;
        const float bo = bout[ok ? col : (N_OUT - 1)];
        #pragma unroll
        for (int fm = 0; fm < 4; ++fm) {
            #pragma unroll
            for (int j = 0; j < 4; ++j) {
                if (ok) {
                    const int row = rbase + fm * 16 + j;
                    const float z = acc[fm][fn][j] + bo;
                    out[(size_t)row * N_OUT + col] = 1.f / (1.f + __expf(-z));
                }
            }
        }
    }
}

// ---------------- fallback: fused f32->bf16 inside GEMM (round-1 kernel) ----------------
__global__ __launch_bounds__(256, 2) void gemm_out_fused(
    const ushort* __restrict__ h3, const float* __restrict__ Wout,
    const float* __restrict__ bout, float* __restrict__ out)
{
    __shared__ __align__(16) ushort Alds[2][128 * 64];
    __shared__ __align__(16) ushort Blds[2][64 * 128];

    const int tid = threadIdx.x;
    const int lane = tid & 63;
    const int w = tid >> 6;
    const int wm = w >> 1, wn = w & 1;

    const int raw = blockIdx.x;
    const int panel = (raw >> 6) * 8 + (raw & 7);
    const int mblk = (raw >> 3) & 7;
    if (panel >= NPANEL) return;
    const int m0 = mblk * 128;
    const int n0 = panel * 128;

    const int nl = tid & 127;
    const int kb0 = tid >> 7;
    int nc = n0 + nl; if (nc > N_OUT - 1) nc = N_OUT - 1;
    const float* Bsrc = Wout + nc;

    f32x4 acc[4][4] = {};
    float breg[32];

    const int arow = wm * 64 + (lane & 15);
    const int ac0  = lane >> 4;
    const int bn   = wn * 64 + (lane & 15);

    auto stageA = [&](int buf, int kt) {
        const int k0 = kt * 64;
        #pragma unroll
        for (int i = 0; i < 4; ++i) {
            const int u = (w * 4 + i) * 64 + lane;
            const int r = u >> 3, cc = u & 7;
            const ushort* src = h3 + (size_t)(m0 + r) * K_DIM + (k0 + ((cc ^ (r & 7)) << 3));
            lds_load16(src, (void*)&Alds[buf][(w * 4 + i) * 512]);
        }
    };
    auto loadB = [&](int kt) {
        const int k0 = kt * 64;
        #pragma unroll
        for (int g = 0; g < 4; ++g) {
            const int kb = kb0 + g * 2;
            #pragma unroll
            for (int i = 0; i < 8; ++i)
                breg[g * 8 + i] = Bsrc[(size_t)(k0 + kb * 8 + i) * N_OUT];
        }
    };
    auto writeB = [&](int buf) {
        #pragma unroll
        for (int g = 0; g < 4; ++g) {
            const int kb = kb0 + g * 2;
            s16x8 v;
            #pragma unroll
            for (int i = 0; i < 8; ++i) v[i] = (short)f2bf(breg[g * 8 + i]);
            *reinterpret_cast<s16x8*>(&Blds[buf][(kb * 128 + nl) * 8]) = v;
        }
    };
    auto compute = [&](int buf) {
        #pragma unroll
        for (int ks = 0; ks < 2; ++ks) {
            s16x8 af[4], bfr[4];
            #pragma unroll
            for (int fm = 0; fm < 4; ++fm) {
                const int r = arow + fm * 16;
                const int cc = (ks * 4 + ac0) ^ (r & 7);
                af[fm] = *reinterpret_cast<const s16x8*>(&Alds[buf][r * 64 + cc * 8]);
            }
            const int kb = ks * 4 + ac0;
            #pragma unroll
            for (int fn = 0; fn < 4; ++fn)
                bfr[fn] = *reinterpret_cast<const s16x8*>(&Blds[buf][(kb * 128 + bn + fn * 16) * 8]);
            #pragma unroll
            for (int fm = 0; fm < 4; ++fm)
                #pragma unroll
                for (int fn = 0; fn < 4; ++fn)
                    acc[fm][fn] = __builtin_amdgcn_mfma_f32_16x16x32_bf16(
                        af[fm], bfr[fn], acc[fm][fn], 0, 0, 0);
        }
    };

    stageA(0, 0);
    loadB(0);
    writeB(0);
    __syncthreads();

    for (int kt = 0; kt < 16; ++kt) {
        const int buf = kt & 1;
        if (kt + 1 < 16) {
            stageA(buf ^ 1, kt + 1);
            loadB(kt + 1);
        }
        compute(buf);
        if (kt + 1 < 16) writeB(buf ^ 1);
        __syncthreads();
    }

    const int rbase = m0 + wm * 64 + (lane >> 4) * 4;
    #pragma unroll
    for (int fn = 0; fn < 4; ++fn) {
        const int col = n0 + wn * 64 + fn * 16 + (lane & 15);
        const bool ok = col < N_OUT;
        const float bo = bout[ok ? col : (N_OUT - 1)];
        #pragma unroll
        for (int fm = 0; fm < 4; ++fm) {
            #pragma unroll
            for (int j = 0; j < 4; ++j) {
                if (ok) {
                    const int row = rbase + fm * 16 + j;
                    const float z = acc[fm][fn][j] + bo;
                    out[(size_t)row * N_OUT + col] = 1.f / (1.f + __expf(-z));
                }
            }
        }
    }
}

extern "C" void kernel_launch(void* const* d_in, const int* in_sizes, int n_in,
                              void* d_out, int out_size, void* d_ws, size_t ws_size,
                              hipStream_t stream)
{
    const float* noise = (const float*)d_in[0];
    const int*   orders = (const int*)d_in[1];
    const float* emb   = (const float*)d_in[2];
    const float* W1 = (const float*)d_in[3];
    const float* b1 = (const float*)d_in[4];
    const float* W2 = (const float*)d_in[5];
    const float* b2 = (const float*)d_in[6];
    const float* W3 = (const float*)d_in[7];
    const float* b3 = (const float*)d_in[8];
    const float* Wout = (const float*)d_in[9];
    const float* bout = (const float*)d_in[10];

    char* ws = (char*)d_ws;
    float*  x  = (float*)(ws);               // 1024*116*4 = 475 KB
    float*  h1 = (float*)(ws + 0x80000);     // 1 MB
    float*  h2 = (float*)(ws + 0x180000);    // 2 MB
    ushort* h3 = (ushort*)(ws + 0x380000);   // 2 MB (bf16)
    ushort* Bp = (ushort*)(ws + 0x580000);   // 517*128*128*8*2 = 135.5 MB
    const size_t need = 0x580000 + (size_t)NPANEL * 128 * 128 * 8 * 2;

    const bool pre = (ws_size >= need);

    if (pre) convert_wout<<<NPANEL * 64, 256, 0, stream>>>(Wout, Bp);
    build_x<<<464, 256, 0, stream>>>(noise, orders, emb, x);
    gemm_relu<false><<<dim3(16, 4),  256, 0, stream>>>(x,  W1, b1, (void*)h1, 1024, 256,  116);
    gemm_relu<false><<<dim3(16, 8),  256, 0, stream>>>(h1, W2, b2, (void*)h2, 1024, 512,  256);
    gemm_relu<true ><<<dim3(16, 16), 256, 0, stream>>>(h2, W3, b3, (void*)h3, 1024, 1024, 512);
    if (pre)
        gemm_out<<<4160, 256, 0, stream>>>(h3, Bp, bout, (float*)d_out);
    else
        gemm_out_fused<<<4160, 256, 0, stream>>>(h3, Wout, bout, (float*)d_out);
}